// Round 13
// baseline (138.373 us; speedup 1.0000x reference)
//
#include <hip/hip_runtime.h>
#include <math.h>

#define C_DIM 192
#define N_ST 16
#define K_DIR 4
#define D_RK 12
#define B_SZ 2
#define H_SZ 64
#define W_SZ 64
#define L_SZ 4096
#define DPROJ 44   // D_RK + 2*N_ST
#define NCHUNK 64
#define TCHUNK 64  // L_SZ / NCHUNK

typedef short bf16x8 __attribute__((ext_vector_type(8)));
typedef float f32x4 __attribute__((ext_vector_type(4)));

__device__ __forceinline__ float sigmoidf_(float x) { return 1.f / (1.f + __expf(-x)); }

// f32 -> bf16 (round-to-nearest-even), as raw ushort
__device__ __forceinline__ unsigned short f2bf(float f) {
    unsigned u = __builtin_bit_cast(unsigned, f);
    return (unsigned short)((u + 0x7FFFu + ((u >> 16) & 1u)) >> 16);
}
__device__ __forceinline__ float bfhi(unsigned p) {           // hi bf16 -> f32
    return __builtin_bit_cast(float, p & 0xFFFF0000u);
}
__device__ __forceinline__ float bflo(unsigned p) {           // lo bf16 -> f32
    return __builtin_bit_cast(float, p << 16);
}

// scan-order index t <-> memory index l (involution for every k)
__device__ __forceinline__ int scan_map(int k, int t) {
    int te = (k & 1) ? (L_SZ - 1 - t) : t;
    return (k >= 2) ? (((te & 63) << 6) | (te >> 6)) : te;  // transpose HxW (64x64)
}

// Aprod scratch lives in the dead x_ssm half of xz (cols 0..191 of each 384-row)
__device__ __forceinline__ size_t apr_idx(unsigned o) {
    unsigned r = o / 192u;
    unsigned m = o - r * 192u;
    return (size_t)r * 384u + m;
}

// ---- one-time weight conversion -> bf16 MFMA fragments ----
__global__ __launch_bounds__(256) void wconv_all(const float* __restrict__ ipw,
        const float* __restrict__ xpw, const float* __restrict__ dtw,
        const float* __restrict__ ow,
        unsigned short* __restrict__ Wip, unsigned short* __restrict__ Wt_g,
        unsigned short* __restrict__ Dw_g, unsigned short* __restrict__ Wout)
{
    int idx = blockIdx.x * 256 + threadIdx.x;   // 0 .. 172031
    if (idx < 73728) {                          // in_proj_w
        int kg = idx / 3072;                    // 384*8
        int rem = idx - kg * 3072;
        int col = rem >> 3, j = rem & 7;
        Wip[idx] = f2bf(ipw[(size_t)(kg * 8 + j) * 384 + col]);
    } else if (idx < 110592) {                  // x_proj_w
        int i2 = idx - 73728;
        int k = i2 / 9216;
        int rem = i2 - k * 9216;
        int kg = rem / 384;
        int r2 = rem - kg * 384;
        int col = r2 >> 3, j = r2 & 7;
        int kr = kg * 8 + j;
        float v = (col < DPROJ) ? xpw[(size_t)k * C_DIM * DPROJ + kr * DPROJ + col] : 0.f;
        Wt_g[i2] = f2bf(v);
    } else if (idx < 135168) {                  // dt_w
        int i3 = idx - 110592;
        int k = i3 / 6144;
        int rem = i3 - k * 6144;
        int kb2 = rem / 1536;
        int r2 = rem - kb2 * 1536;
        int c = r2 >> 3, j = r2 & 7;
        int kr = kb2 * 8 + j;
        float v = (kr < D_RK) ? dtw[(size_t)k * D_RK * C_DIM + kr * C_DIM + c] : 0.f;
        Dw_g[i3] = f2bf(v);
    } else {                                    // out_w
        int i4 = idx - 135168;
        int kg = i4 / 1536;                     // 192*8
        int rem = i4 - kg * 1536;
        int col = rem >> 3, j = rem & 7;
        Wout[i4] = f2bf(ow[(size_t)(kg * 8 + j) * C_DIM + col]);
    }
}

// MFMA GEMM: C(MxN) = A(Mx192 f32) @ W(192xN bf16 fragments [kg][col][8]).
__global__ __launch_bounds__(256) void gemm_bf16(const float* __restrict__ A,
        const unsigned short* __restrict__ Wt, float* __restrict__ Cc, int N)
{
    __shared__ __align__(16) unsigned short Abt[32 * 25 * 8];  // 12.8 KB
    const int tid = threadIdx.x;
    const int m0 = blockIdx.x * 32;
    const int col0 = blockIdx.y * 192;

    #pragma unroll
    for (int it = 0; it < 3; ++it) {
        int idx = tid + it * 256;            // 768 = 32 rows * 24 kg
        int r = idx / 24, g = idx - r * 24;
        const float* src = &A[((size_t)(m0 + r)) * C_DIM + g * 8];
        float4 v0 = *(const float4*)src;
        float4 v1 = *(const float4*)(src + 4);
        uint4 w;
        w.x = f2bf(v0.x) | ((unsigned)f2bf(v0.y) << 16);
        w.y = f2bf(v0.z) | ((unsigned)f2bf(v0.w) << 16);
        w.z = f2bf(v1.x) | ((unsigned)f2bf(v1.y) << 16);
        w.w = f2bf(v1.z) | ((unsigned)f2bf(v1.w) << 16);
        *(uint4*)&Abt[(r * 25 + g) * 8] = w;
    }
    __syncthreads();

    const int wv = tid >> 6;
    const int ln = tid & 63;
    const int rw = ln & 15;
    const int kq = ln >> 4;
    const int mt = wv >> 1;
    const int nh = wv & 1;

    f32x4 acc[6];
    #pragma unroll
    for (int nt = 0; nt < 6; ++nt) acc[nt] = (f32x4){0.f, 0.f, 0.f, 0.f};

    #pragma unroll
    for (int ks = 0; ks < 6; ++ks) {
        int kg = ks * 4 + kq;
        bf16x8 a = *(const bf16x8*)&Abt[((mt * 16 + rw) * 25 + kg) * 8];
        #pragma unroll
        for (int nt = 0; nt < 6; ++nt) {
            int col = col0 + nh * 96 + nt * 16 + rw;
            bf16x8 b = *(const bf16x8*)&Wt[((size_t)kg * N + col) * 8];
            acc[nt] = __builtin_amdgcn_mfma_f32_16x16x32_bf16(a, b, acc[nt], 0, 0, 0);
        }
    }
    #pragma unroll
    for (int nt = 0; nt < 6; ++nt)
        #pragma unroll
        for (int i = 0; i < 4; ++i) {
            int row = m0 + mt * 16 + kq * 4 + i;
            int col = col0 + nh * 96 + nt * 16 + rw;
            Cc[(size_t)row * N + col] = acc[nt][i];
        }
}

// depthwise 3x3 SAME conv + bias + SiLU -> xc (B,L,C). Sliding-window over w.
__global__ __launch_bounds__(192) void conv_silu(const float* __restrict__ xz,
        const float* __restrict__ cw, const float* __restrict__ cb, float* __restrict__ xc)
{
    const int c = threadIdx.x;
    const int h = blockIdx.x;
    const int w0 = blockIdx.y * 32;
    const int b = blockIdx.z;
    float wg[9];
    #pragma unroll
    for (int i = 0; i < 9; ++i) wg[i] = cw[c * 9 + i];
    const float* base = xz + ((size_t)b * L_SZ + (size_t)h * W_SZ) * (2 * C_DIM) + c;
    const bool hm = (h > 0), hp = (h < H_SZ - 1);
    const int RS = W_SZ * 2 * C_DIM;  // 24576
    float cL[3], cC[3], cR[3];
    #define LDCOL(w, dst) { \
        int off_ = (w) * (2 * C_DIM); \
        dst[0] = hm ? base[off_ - RS] : 0.f; \
        dst[1] = base[off_]; \
        dst[2] = hp ? base[off_ + RS] : 0.f; }
    if (w0 > 0) { LDCOL(w0 - 1, cL) } else { cL[0] = cL[1] = cL[2] = 0.f; }
    LDCOL(w0, cC)
    const float bias = cb[c];
    for (int w = w0; w < w0 + 32; ++w) {
        if (w < W_SZ - 1) { LDCOL(w + 1, cR) } else { cR[0] = cR[1] = cR[2] = 0.f; }
        float acc = bias;
        #pragma unroll
        for (int r = 0; r < 3; ++r)
            acc += cL[r] * wg[r * 3] + cC[r] * wg[r * 3 + 1] + cR[r] * wg[r * 3 + 2];
        float v = acc * sigmoidf_(acc);
        xc[((size_t)b * L_SZ + h * W_SZ + w) * C_DIM + c] = v;
        cL[0] = cC[0]; cL[1] = cC[1]; cL[2] = cC[2];
        cC[0] = cR[0]; cC[1] = cR[1]; cC[2] = cR[2];
    }
    #undef LDCOL
}

// FUSED proj + scan_part1. Block = one scan-order chunk (64 t) of one (k,b).
// Phase A: gather rows via scan_map, MFMA proj, delta, contiguous dq/B/C writes.
// Phase B (same block, after barrier): S1 recurrence reading dq from L2,
// B from pj LDS -> Aprod (xz scratch) + Bsum (hb).
__global__ __launch_bounds__(256) void proj_scan1(const float* __restrict__ xc,
        const unsigned short* __restrict__ Wt_g, const unsigned short* __restrict__ Dw_g,
        const float* __restrict__ dtb, const float* __restrict__ A_logs,
        unsigned* __restrict__ dq,
        float* __restrict__ Bm, float* __restrict__ Cm,
        float* __restrict__ Apr, float* __restrict__ hb)
{
    __shared__ __align__(16) unsigned short Abt[64 * 25 * 8];  // 25.6 KB
    __shared__ __align__(16) unsigned short pjd[64 * 32];      // 4 KB
    __shared__ __align__(16) float pj[64][56];                 // 14.3 KB (16B-aligned rows)

    const int tid = threadIdx.x;
    const int ch = blockIdx.x;
    const int k  = blockIdx.y;
    const int b  = blockIdx.z;
    const int kbi = k * B_SZ + b;
    const int t0 = ch * TCHUNK;

    // ---- stage A: 64 scan-order rows (gathered via involution), f32 -> bf16 ----
    #pragma unroll
    for (int it = 0; it < 6; ++it) {
        int idx = tid + it * 256;            // 1536 = 64 rows * 24 kgroups
        int r = idx / 24, g = idx - r * 24;
        int li = scan_map(k, t0 + r);
        const float* src = &xc[((size_t)b * L_SZ + li) * C_DIM + g * 8];
        float4 v0 = *(const float4*)src;
        float4 v1 = *(const float4*)(src + 4);
        uint4 w;
        w.x = f2bf(v0.x) | ((unsigned)f2bf(v0.y) << 16);
        w.y = f2bf(v0.z) | ((unsigned)f2bf(v0.w) << 16);
        w.z = f2bf(v1.x) | ((unsigned)f2bf(v1.y) << 16);
        w.w = f2bf(v1.z) | ((unsigned)f2bf(v1.w) << 16);
        *(uint4*)&Abt[(r * 25 + g) * 8] = w;
    }
    ((uint4*)pjd)[tid] = make_uint4(0, 0, 0, 0);   // all 256 uint4s
    __syncthreads();

    const int wv = tid >> 6;
    const int ln = tid & 63;
    const int rw = ln & 15;
    const int kq = ln >> 4;

    // ---- GEMM1: proj (W fragments straight from global, L2-hot) ----
    const unsigned short* wk = Wt_g + (size_t)k * 9216;
    f32x4 acc0 = {0.f, 0.f, 0.f, 0.f}, acc1 = acc0, acc2 = acc0;
    #pragma unroll
    for (int ks = 0; ks < 6; ++ks) {
        int kg = ks * 4 + kq;
        bf16x8 a  = *(const bf16x8*)&Abt[((wv * 16 + rw) * 25 + kg) * 8];
        bf16x8 b0 = *(const bf16x8*)&wk[(kg * 48 + rw) * 8];
        bf16x8 b1 = *(const bf16x8*)&wk[(kg * 48 + 16 + rw) * 8];
        bf16x8 b2 = *(const bf16x8*)&wk[(kg * 48 + 32 + rw) * 8];
        acc0 = __builtin_amdgcn_mfma_f32_16x16x32_bf16(a, b0, acc0, 0, 0, 0);
        acc1 = __builtin_amdgcn_mfma_f32_16x16x32_bf16(a, b1, acc1, 0, 0, 0);
        acc2 = __builtin_amdgcn_mfma_f32_16x16x32_bf16(a, b2, acc2, 0, 0, 0);
    }
    #pragma unroll
    for (int i = 0; i < 4; ++i) {
        int row = wv * 16 + kq * 4 + i;
        pj[row][rw]      = acc0[i];
        pj[row][16 + rw] = acc1[i];
        pj[row][32 + rw] = acc2[i];
        if (rw < D_RK) pjd[row * 32 + rw] = f2bf(acc0[i]);
    }
    __syncthreads();

    // ---- GEMM2: delta logits ----
    const unsigned short* dwk = Dw_g + (size_t)k * 6144;
    bf16x8 a2 = *(const bf16x8*)&pjd[(wv * 16 + rw) * 32 + kq * 8];
    f32x4 d2[12];
    #pragma unroll
    for (int nt = 0; nt < 12; ++nt) {
        bf16x8 b2 = *(const bf16x8*)&dwk[(kq * 192 + nt * 16 + rw) * 8];
        f32x4 z = {0.f, 0.f, 0.f, 0.f};
        d2[nt] = __builtin_amdgcn_mfma_f32_16x16x32_bf16(a2, b2, z, 0, 0, 0);
    }

    // ---- delta/du -> packed dq (contiguous writes); u from LDS A-tile ----
    #pragma unroll
    for (int nt = 0; nt < 12; ++nt) {
        int c = nt * 16 + rw;
        int g8 = c >> 3, j = c & 7;
        float dtb2 = 2.f * dtb[k * C_DIM + c];
        #pragma unroll
        for (int i = 0; i < 4; ++i) {
            int row = wv * 16 + kq * 4 + i;
            float s = d2[nt][i] + dtb2;
            float sp = (s > 15.f) ? s : __logf(1.f + __expf(s));
            float u = __builtin_bit_cast(float,
                        (unsigned)Abt[(row * 25 + g8) * 8 + j] << 16);
            size_t oi = ((size_t)kbi * L_SZ + t0 + row) * C_DIM + c;
            dq[oi] = ((unsigned)f2bf(sp) << 16) | (unsigned)f2bf(sp * u);
        }
    }
    #pragma unroll
    for (int j = 0; j < 4; ++j) {
        int o = tid + j * 256;               // 1024 = 64*16
        int ll = o >> 4, n = o & 15;
        size_t oo = ((size_t)kbi * L_SZ + t0 + ll) * N_ST + n;
        Bm[oo] = pj[ll][D_RK + n];
        Cm[oo] = pj[ll][D_RK + N_ST + n];
    }
    __syncthreads();   // dq visible block-wide (vmcnt drained)

    // ---- phase B: S1 recurrence (dq from L2, B from pj LDS) ----
    const unsigned* pq = dq + ((size_t)kbi * L_SZ + t0) * C_DIM;
    #pragma unroll
    for (int z = 0; z < 3; ++z) {
        int uu = tid + z * 256;              // 0..767
        int g = uu / 192;
        int c = uu - g * 192;
        const float4 Alg = *(const float4*)&A_logs[((size_t)k * C_DIM + c) * N_ST + g * 4];
        const float An0 = -__expf(Alg.x) * 1.44269504089f;
        const float An1 = -__expf(Alg.y) * 1.44269504089f;
        const float An2 = -__expf(Alg.z) * 1.44269504089f;
        const float An3 = -__expf(Alg.w) * 1.44269504089f;
        float h0 = 0.f, h1 = 0.f, h2 = 0.f, h3 = 0.f, dsum = 0.f;
        #pragma unroll 4
        for (int t = 0; t < TCHUNK; ++t) {
            unsigned pk = pq[(size_t)t * C_DIM + c];
            float dlt = bfhi(pk);
            float qv  = bflo(pk);
            float4 B4 = *(const float4*)&pj[t][D_RK + g * 4];
            dsum += dlt;
            h0 = fmaf(__builtin_amdgcn_exp2f(dlt * An0), h0, qv * B4.x);
            h1 = fmaf(__builtin_amdgcn_exp2f(dlt * An1), h1, qv * B4.y);
            h2 = fmaf(__builtin_amdgcn_exp2f(dlt * An2), h2, qv * B4.z);
            h3 = fmaf(__builtin_amdgcn_exp2f(dlt * An3), h3, qv * B4.w);
        }
        unsigned o = ((unsigned)(ch * K_DIR * B_SZ + kbi) * C_DIM + c) * N_ST + g * 4;
        float4 Ap4;
        Ap4.x = __builtin_amdgcn_exp2f(dsum * An0);
        Ap4.y = __builtin_amdgcn_exp2f(dsum * An1);
        Ap4.z = __builtin_amdgcn_exp2f(dsum * An2);
        Ap4.w = __builtin_amdgcn_exp2f(dsum * An3);
        *(float4*)&Apr[apr_idx(o)] = Ap4;
        *(float4*)&hb[o] = make_float4(h0, h1, h2, h3);
    }
}

// S2: sequential compose over chunks; hb: reads Bsum, writes hinit (same buffer).
__global__ __launch_bounds__(256) void scan_part2(const float* __restrict__ Apr,
        float* hb)
{
    const int kb = blockIdx.y;
    const int wave = threadIdx.x >> 6;
    const int lane = threadIdx.x & 63;
    const int ci = lane >> 4;
    const int n = lane & 15;
    const int c = blockIdx.x * 16 + wave * 4 + ci;
    float h = 0.f;
    #pragma unroll 8
    for (int ch = 0; ch < NCHUNK; ++ch) {
        unsigned o = ((unsigned)(ch * K_DIR * B_SZ + kb) * C_DIM + c) * N_ST + n;
        float Ap = Apr[apr_idx(o)];
        float Bs = hb[o];
        hb[o] = h;                 // hinit (exclusive prefix)
        h = fmaf(Ap, h, Bs);
    }
}

// S3: re-run chunk from hinit; y = sum_n h*C -> ys (f32).
__global__ __launch_bounds__(256) void scan_part3(const unsigned* __restrict__ dq,
        const float* __restrict__ Bm, const float* __restrict__ Cm,
        const float* __restrict__ A_logs, const float* __restrict__ hb,
        float* __restrict__ ys)
{
    __shared__ float B_s[TCHUNK][16];
    __shared__ float C_s[TCHUNK][16];
    const int c0 = blockIdx.x * 64;
    const int kb = blockIdx.y;
    const int k = kb >> 1;
    const int ch = blockIdx.z;
    const int tid = threadIdx.x;
    ((float4*)B_s)[tid] = ((const float4*)(Bm + ((size_t)kb * L_SZ + ch * TCHUNK) * N_ST))[tid];
    ((float4*)C_s)[tid] = ((const float4*)(Cm + ((size_t)kb * L_SZ + ch * TCHUNK) * N_ST))[tid];
    __syncthreads();

    const int w = tid >> 6, ln = tid & 63;
    const int cl = ln & 15, g = ln >> 4;
    const int c = c0 + w * 16 + cl;
    const float4 Alg = *(const float4*)&A_logs[((size_t)k * C_DIM + c) * N_ST + g * 4];
    const float An0 = -__expf(Alg.x) * 1.44269504089f;
    const float An1 = -__expf(Alg.y) * 1.44269504089f;
    const float An2 = -__expf(Alg.z) * 1.44269504089f;
    const float An3 = -__expf(Alg.w) * 1.44269504089f;
    const size_t tbase = ((size_t)kb * L_SZ + ch * TCHUNK) * C_DIM + c;
    const unsigned* pq = dq + tbase;
    float* yp = ys + tbase;
    unsigned o = ((unsigned)(ch * K_DIR * B_SZ + kb) * C_DIM + c) * N_ST + g * 4;
    float4 hv = *(const float4*)&hb[o];
    float h0 = hv.x, h1 = hv.y, h2 = hv.z, h3 = hv.w;
    #pragma unroll 4
    for (int t = 0; t < TCHUNK; ++t) {
        unsigned pk = pq[(size_t)t * C_DIM];
        float dlt = bfhi(pk);
        float qv  = bflo(pk);
        float4 B4 = *(const float4*)&B_s[t][g * 4];
        float4 C4 = *(const float4*)&C_s[t][g * 4];
        h0 = fmaf(__builtin_amdgcn_exp2f(dlt * An0), h0, qv * B4.x);
        h1 = fmaf(__builtin_amdgcn_exp2f(dlt * An1), h1, qv * B4.y);
        h2 = fmaf(__builtin_amdgcn_exp2f(dlt * An2), h2, qv * B4.z);
        h3 = fmaf(__builtin_amdgcn_exp2f(dlt * An3), h3, qv * B4.w);
        float p = h0 * C4.x;
        p = fmaf(h1, C4.y, p);
        p = fmaf(h2, C4.z, p);
        p = fmaf(h3, C4.w, p);
        p += __shfl_xor(p, 16);
        p += __shfl_xor(p, 32);
        if (g == 0) yp[(size_t)t * C_DIM] = p;
    }
}

// fused: gather 4 dirs + Ds*xc + LayerNorm + *silu(z) + out GEMM (MFMA).
__global__ __launch_bounds__(256) void ln_gemm_fused(const float* __restrict__ ys,
        const float* __restrict__ xz, const float* __restrict__ xc,
        const float* __restrict__ Dsv, const float* __restrict__ g,
        const float* __restrict__ bb, const unsigned short* __restrict__ Wout,
        float* __restrict__ outp)
{
    __shared__ __align__(16) unsigned short Abt[32 * 25 * 8];
    __shared__ float ds4s[C_DIM];
    const int tid = threadIdx.x;
    const int m0 = blockIdx.x * 32;

    if (tid < C_DIM)
        ds4s[tid] = Dsv[tid] + Dsv[C_DIM + tid] + Dsv[2 * C_DIM + tid] + Dsv[3 * C_DIM + tid];
    __syncthreads();

    // ---- phase 1: LN + silu -> bf16 fragments ----
    {
        const int r = tid >> 3;            // row 0..31
        const int t8 = tid & 7;            // 8 threads per row, 24 cols each
        const int row = m0 + r;
        const int b = row >> 12, l = row & (L_SZ - 1);
        const int l2 = ((l & 63) << 6) | (l >> 6);
        const float* r0 = ys + ((size_t)(0 * B_SZ + b) * L_SZ + l) * C_DIM;
        const float* r1 = ys + ((size_t)(1 * B_SZ + b) * L_SZ + (L_SZ - 1 - l)) * C_DIM;
        const float* r2 = ys + ((size_t)(2 * B_SZ + b) * L_SZ + l2) * C_DIM;
        const float* r3 = ys + ((size_t)(3 * B_SZ + b) * L_SZ + (L_SZ - 1 - l2)) * C_DIM;
        const float* xcr = xc + (size_t)row * C_DIM;
        float4 v[6];
        float s = 0.f, s2 = 0.f;
        #pragma unroll
        for (int q = 0; q < 6; ++q) {
            int cc = t8 * 24 + q * 4;
            float4 a0 = *(const float4*)&r0[cc];
            float4 a1 = *(const float4*)&r1[cc];
            float4 a2 = *(const float4*)&r2[cc];
            float4 a3 = *(const float4*)&r3[cc];
            float4 xv = *(const float4*)&xcr[cc];
            float4 dd = *(const float4*)&ds4s[cc];
            float4 vv;
            vv.x = a0.x + a1.x + a2.x + a3.x + dd.x * xv.x;
            vv.y = a0.y + a1.y + a2.y + a3.y + dd.y * xv.y;
            vv.z = a0.z + a1.z + a2.z + a3.z + dd.z * xv.z;
            vv.w = a0.w + a1.w + a2.w + a3.w + dd.w * xv.w;
            v[q] = vv;
            s += vv.x + vv.y + vv.z + vv.w;
            s2 += vv.x * vv.x + vv.y * vv.y + vv.z * vv.z + vv.w * vv.w;
        }
        s += __shfl_xor(s, 1); s2 += __shfl_xor(s2, 1);
        s += __shfl_xor(s, 2); s2 += __shfl_xor(s2, 2);
        s += __shfl_xor(s, 4); s2 += __shfl_xor(s2, 4);
        float mu = s / C_DIM;
        float var = s2 / C_DIM - mu * mu;
        float rstd = rsqrtf(var + 1e-5f);
        const float* zr = xz + (size_t)row * (2 * C_DIM) + C_DIM;
        unsigned short ob[24];
        #pragma unroll
        for (int q = 0; q < 6; ++q) {
            int cc = t8 * 24 + q * 4;
            float4 gv = *(const float4*)&g[cc];
            float4 bv = *(const float4*)&bb[cc];
            float4 zv = *(const float4*)&zr[cc];
            float t0 = (v[q].x - mu) * rstd * gv.x + bv.x;
            float t1 = (v[q].y - mu) * rstd * gv.y + bv.y;
            float t2 = (v[q].z - mu) * rstd * gv.z + bv.z;
            float t3 = (v[q].w - mu) * rstd * gv.w + bv.w;
            ob[q * 4 + 0] = f2bf(t0 * (zv.x * sigmoidf_(zv.x)));
            ob[q * 4 + 1] = f2bf(t1 * (zv.y * sigmoidf_(zv.y)));
            ob[q * 4 + 2] = f2bf(t2 * (zv.z * sigmoidf_(zv.z)));
            ob[q * 4 + 3] = f2bf(t3 * (zv.w * sigmoidf_(zv.w)));
        }
        #pragma unroll
        for (int gi = 0; gi < 3; ++gi) {
            uint4 w;
            w.x = ob[gi * 8 + 0] | ((unsigned)ob[gi * 8 + 1] << 16);
            w.y = ob[gi * 8 + 2] | ((unsigned)ob[gi * 8 + 3] << 16);
            w.z = ob[gi * 8 + 4] | ((unsigned)ob[gi * 8 + 5] << 16);
            w.w = ob[gi * 8 + 6] | ((unsigned)ob[gi * 8 + 7] << 16);
            *(uint4*)&Abt[(r * 25 + t8 * 3 + gi) * 8] = w;
        }
    }
    __syncthreads();

    // ---- phase 2: out GEMM ----
    const int wv = tid >> 6;
    const int ln = tid & 63;
    const int rw = ln & 15;
    const int kq = ln >> 4;
    const int mt = wv >> 1;
    const int nh = wv & 1;

    f32x4 acc[6];
    #pragma unroll
    for (int nt = 0; nt < 6; ++nt) acc[nt] = (f32x4){0.f, 0.f, 0.f, 0.f};
    #pragma unroll
    for (int ks = 0; ks < 6; ++ks) {
        int kg = ks * 4 + kq;
        bf16x8 a = *(const bf16x8*)&Abt[((mt * 16 + rw) * 25 + kg) * 8];
        #pragma unroll
        for (int nt = 0; nt < 6; ++nt) {
            int col = nh * 96 + nt * 16 + rw;
            bf16x8 b = *(const bf16x8*)&Wout[((size_t)kg * C_DIM + col) * 8];
            acc[nt] = __builtin_amdgcn_mfma_f32_16x16x32_bf16(a, b, acc[nt], 0, 0, 0);
        }
    }
    #pragma unroll
    for (int nt = 0; nt < 6; ++nt)
        #pragma unroll
        for (int i = 0; i < 4; ++i) {
            int row = m0 + mt * 16 + kq * 4 + i;
            int col = nh * 96 + nt * 16 + rw;
            outp[(size_t)row * C_DIM + col] = acc[nt][i];
        }
}

extern "C" void kernel_launch(void* const* d_in, const int* in_sizes, int n_in,
                              void* d_out, int out_size, void* d_ws, size_t ws_size,
                              hipStream_t stream)
{
    const float* x         = (const float*)d_in[0];
    const float* in_proj_w = (const float*)d_in[1];
    const float* conv_w    = (const float*)d_in[2];
    const float* conv_b    = (const float*)d_in[3];
    const float* x_proj_w  = (const float*)d_in[4];
    const float* dt_w      = (const float*)d_in[5];
    const float* dt_b      = (const float*)d_in[6];
    const float* A_logs    = (const float*)d_in[7];
    const float* Ds        = (const float*)d_in[8];
    const float* ln_g      = (const float*)d_in[9];
    const float* ln_b      = (const float*)d_in[10];
    const float* out_w     = (const float*)d_in[11];
    float* out = (float*)d_out;
    float* ws = (float*)d_ws;

    const size_t M = (size_t)B_SZ * L_SZ;          // 8192
    const size_t KM = (size_t)K_DIR * M;           // 32768
    const size_t HBSZ = (size_t)NCHUNK * K_DIR * B_SZ * C_DIM * N_ST;  // 1.57M floats

    float* xz      = ws;                           // M*384 (x_ssm half -> Apr scratch)
    float* xc      = xz + M * 384;                 // M*192
    unsigned* dq   = (unsigned*)(xc + M * C_DIM);  // KM*192 packed bf16 (delta,du)
    float* ys      = (float*)(dq + KM * C_DIM);    // KM*192
    float* Bm      = ys + KM * C_DIM;              // KM*16
    float* Cm      = Bm + KM * N_ST;               // KM*16
    float* hb      = Cm + KM * N_ST;               // HBSZ : Bsum then hinit
    // weight fragments PAST hb (hb is written concurrently inside proj_scan1!)
    unsigned short* Wt_g = (unsigned short*)(hb + HBSZ);   // 4*9216
    unsigned short* Dw_g = Wt_g + 4 * 9216;                // 4*6144
    unsigned short* Wip  = Dw_g + 4 * 6144;                // 73728
    unsigned short* Wout = Wip + 73728;                    // 36864

    wconv_all<<<dim3(672), 256, 0, stream>>>(in_proj_w, x_proj_w, dt_w, out_w, Wip, Wt_g, Dw_g, Wout);
    gemm_bf16<<<dim3(M / 32, 2), 256, 0, stream>>>(x, Wip, xz, 2 * C_DIM);
    conv_silu<<<dim3(H_SZ, 2, B_SZ), 192, 0, stream>>>(xz, conv_w, conv_b, xc);
    proj_scan1<<<dim3(NCHUNK, K_DIR, B_SZ), 256, 0, stream>>>(xc, Wt_g, Dw_g, dt_b, A_logs, dq, Bm, Cm, xz, hb);
    scan_part2<<<dim3(C_DIM / 16, K_DIR * B_SZ), 256, 0, stream>>>(xz, hb);
    scan_part3<<<dim3(C_DIM / 64, K_DIR * B_SZ, NCHUNK), 256, 0, stream>>>(dq, Bm, Cm, A_logs, hb, ys);
    ln_gemm_fused<<<dim3(M / 32), 256, 0, stream>>>(ys, xz, xc, Ds, ln_g, ln_b, Wout, out);
}

// Round 14
// 123.501 us; speedup vs baseline: 1.1204x; 1.1204x over previous
//
#include <hip/hip_runtime.h>
#include <math.h>

#define C_DIM 192
#define N_ST 16
#define K_DIR 4
#define D_RK 12
#define B_SZ 2
#define H_SZ 64
#define W_SZ 64
#define L_SZ 4096
#define DPROJ 44   // D_RK + 2*N_ST
#define NCHUNK 64
#define TCHUNK 64  // L_SZ / NCHUNK

typedef short bf16x8 __attribute__((ext_vector_type(8)));
typedef float f32x4 __attribute__((ext_vector_type(4)));

__device__ __forceinline__ float sigmoidf_(float x) { return 1.f / (1.f + __expf(-x)); }

__device__ __forceinline__ unsigned short f2bf(float f) {
    unsigned u = __builtin_bit_cast(unsigned, f);
    return (unsigned short)((u + 0x7FFFu + ((u >> 16) & 1u)) >> 16);
}
__device__ __forceinline__ float bf2f(unsigned short s) {
    return __builtin_bit_cast(float, (unsigned)s << 16);
}
__device__ __forceinline__ float bfhi(unsigned p) {
    return __builtin_bit_cast(float, p & 0xFFFF0000u);
}
__device__ __forceinline__ float bflo(unsigned p) {
    return __builtin_bit_cast(float, p << 16);
}

// scan-order index t <-> memory index l (involution for every k)
__device__ __forceinline__ int scan_map(int k, int t) {
    int te = (k & 1) ? (L_SZ - 1 - t) : t;
    return (k >= 2) ? (((te & 63) << 6) | (te >> 6)) : te;  // transpose HxW (64x64)
}

// ---- one-time weight conversion -> bf16 MFMA fragments ----
__global__ __launch_bounds__(256) void wconv_all(const float* __restrict__ ipw,
        const float* __restrict__ xpw, const float* __restrict__ dtw,
        const float* __restrict__ ow,
        unsigned short* __restrict__ Wip, unsigned short* __restrict__ Wt_g,
        unsigned short* __restrict__ Dw_g, unsigned short* __restrict__ Wout)
{
    int idx = blockIdx.x * 256 + threadIdx.x;   // 0 .. 172031
    if (idx < 73728) {                          // in_proj_w
        int kg = idx / 3072;                    // 384*8
        int rem = idx - kg * 3072;
        int col = rem >> 3, j = rem & 7;
        Wip[idx] = f2bf(ipw[(size_t)(kg * 8 + j) * 384 + col]);
    } else if (idx < 110592) {                  // x_proj_w
        int i2 = idx - 73728;
        int k = i2 / 9216;
        int rem = i2 - k * 9216;
        int kg = rem / 384;
        int r2 = rem - kg * 384;
        int col = r2 >> 3, j = r2 & 7;
        int kr = kg * 8 + j;
        float v = (col < DPROJ) ? xpw[(size_t)k * C_DIM * DPROJ + kr * DPROJ + col] : 0.f;
        Wt_g[i2] = f2bf(v);
    } else if (idx < 135168) {                  // dt_w
        int i3 = idx - 110592;
        int k = i3 / 6144;
        int rem = i3 - k * 6144;
        int kb2 = rem / 1536;
        int r2 = rem - kb2 * 1536;
        int c = r2 >> 3, j = r2 & 7;
        int kr = kb2 * 8 + j;
        float v = (kr < D_RK) ? dtw[(size_t)k * D_RK * C_DIM + kr * C_DIM + c] : 0.f;
        Dw_g[i3] = f2bf(v);
    } else {                                    // out_w
        int i4 = idx - 135168;
        int kg = i4 / 1536;                     // 192*8
        int rem = i4 - kg * 1536;
        int col = rem >> 3, j = rem & 7;
        Wout[i4] = f2bf(ow[(size_t)(kg * 8 + j) * C_DIM + col]);
    }
}

// in_proj MFMA GEMM with split outputs: blockIdx.y==0 -> xs (cols 0..191),
// blockIdx.y==1 -> zb (cols 192..383). Both outputs dense M x 192.
__global__ __launch_bounds__(256) void gemm_inproj(const float* __restrict__ A,
        const unsigned short* __restrict__ Wt, float* __restrict__ xs,
        float* __restrict__ zb)
{
    __shared__ __align__(16) unsigned short Abt[32 * 25 * 8];  // 12.8 KB
    const int tid = threadIdx.x;
    const int m0 = blockIdx.x * 32;
    const int col0 = blockIdx.y * 192;
    float* outp = blockIdx.y ? zb : xs;

    #pragma unroll
    for (int it = 0; it < 3; ++it) {
        int idx = tid + it * 256;            // 768 = 32 rows * 24 kg
        int r = idx / 24, g = idx - r * 24;
        const float* src = &A[((size_t)(m0 + r)) * C_DIM + g * 8];
        float4 v0 = *(const float4*)src;
        float4 v1 = *(const float4*)(src + 4);
        uint4 w;
        w.x = f2bf(v0.x) | ((unsigned)f2bf(v0.y) << 16);
        w.y = f2bf(v0.z) | ((unsigned)f2bf(v0.w) << 16);
        w.z = f2bf(v1.x) | ((unsigned)f2bf(v1.y) << 16);
        w.w = f2bf(v1.z) | ((unsigned)f2bf(v1.w) << 16);
        *(uint4*)&Abt[(r * 25 + g) * 8] = w;
    }
    __syncthreads();

    const int wv = tid >> 6;
    const int ln = tid & 63;
    const int rw = ln & 15;
    const int kq = ln >> 4;
    const int mt = wv >> 1;
    const int nh = wv & 1;

    f32x4 acc[6];
    #pragma unroll
    for (int nt = 0; nt < 6; ++nt) acc[nt] = (f32x4){0.f, 0.f, 0.f, 0.f};

    #pragma unroll
    for (int ks = 0; ks < 6; ++ks) {
        int kg = ks * 4 + kq;
        bf16x8 a = *(const bf16x8*)&Abt[((mt * 16 + rw) * 25 + kg) * 8];
        #pragma unroll
        for (int nt = 0; nt < 6; ++nt) {
            int col = col0 + nh * 96 + nt * 16 + rw;
            bf16x8 b = *(const bf16x8*)&Wt[((size_t)kg * 384 + col) * 8];
            acc[nt] = __builtin_amdgcn_mfma_f32_16x16x32_bf16(a, b, acc[nt], 0, 0, 0);
        }
    }
    #pragma unroll
    for (int nt = 0; nt < 6; ++nt)
        #pragma unroll
        for (int i = 0; i < 4; ++i) {
            int row = m0 + mt * 16 + kq * 4 + i;
            int col = nh * 96 + nt * 16 + rw;
            outp[(size_t)row * C_DIM + col] = acc[nt][i];
        }
}

// depthwise 3x3 SAME conv + bias + SiLU: xs (B,L,C dense) -> xc (B,L,C).
__global__ __launch_bounds__(192) void conv_silu(const float* __restrict__ xs,
        const float* __restrict__ cw, const float* __restrict__ cb, float* __restrict__ xc)
{
    const int c = threadIdx.x;
    const int h = blockIdx.x;
    const int w0 = blockIdx.y * 32;
    const int b = blockIdx.z;
    float wg[9];
    #pragma unroll
    for (int i = 0; i < 9; ++i) wg[i] = cw[c * 9 + i];
    const float* base = xs + ((size_t)b * L_SZ + (size_t)h * W_SZ) * C_DIM + c;
    const bool hm = (h > 0), hp = (h < H_SZ - 1);
    const int RS = W_SZ * C_DIM;
    float cL[3], cC[3], cR[3];
    #define LDCOL(w, dst) { \
        int off_ = (w) * C_DIM; \
        dst[0] = hm ? base[off_ - RS] : 0.f; \
        dst[1] = base[off_]; \
        dst[2] = hp ? base[off_ + RS] : 0.f; }
    if (w0 > 0) { LDCOL(w0 - 1, cL) } else { cL[0] = cL[1] = cL[2] = 0.f; }
    LDCOL(w0, cC)
    const float bias = cb[c];
    for (int w = w0; w < w0 + 32; ++w) {
        if (w < W_SZ - 1) { LDCOL(w + 1, cR) } else { cR[0] = cR[1] = cR[2] = 0.f; }
        float acc = bias;
        #pragma unroll
        for (int r = 0; r < 3; ++r)
            acc += cL[r] * wg[r * 3] + cC[r] * wg[r * 3 + 1] + cR[r] * wg[r * 3 + 2];
        float v = acc * sigmoidf_(acc);
        xc[((size_t)b * L_SZ + h * W_SZ + w) * C_DIM + c] = v;
        cL[0] = cC[0]; cL[1] = cC[1]; cL[2] = cC[2];
        cC[0] = cR[0]; cC[1] = cR[1]; cC[2] = cR[2];
    }
    #undef LDCOL
}

// MFMA proj: block = 64 memory-order rows x one direction; scatter writes.
__global__ __launch_bounds__(256) void proj_mfma(const float* __restrict__ xc,
        const unsigned short* __restrict__ Wt_g, const unsigned short* __restrict__ Dw_g,
        const float* __restrict__ dtb,
        unsigned* __restrict__ dq,
        float* __restrict__ Bm, float* __restrict__ Cm)
{
    __shared__ __align__(16) unsigned short Abt[64 * 25 * 8];
    __shared__ __align__(16) unsigned short Wt[24 * 48 * 8];
    __shared__ __align__(16) unsigned short Dw[4 * 192 * 8];
    __shared__ __align__(16) unsigned short pjd[64 * 32];
    __shared__ float pj[64][50];

    const int tid = threadIdx.x;
    const int m0 = blockIdx.x * 64;
    const int b  = m0 >> 12;
    const int l0 = m0 & (L_SZ - 1);
    const int k  = blockIdx.y;
    const int kbi = k * B_SZ + b;

    #pragma unroll
    for (int it = 0; it < 6; ++it) {
        int idx = tid + it * 256;            // 1536 = 64 rows * 24 kgroups
        int r = idx / 24, g = idx - r * 24;
        const float* src = &xc[((size_t)(m0 + r)) * C_DIM + g * 8];
        float4 v0 = *(const float4*)src;
        float4 v1 = *(const float4*)(src + 4);
        uint4 w;
        w.x = f2bf(v0.x) | ((unsigned)f2bf(v0.y) << 16);
        w.y = f2bf(v0.z) | ((unsigned)f2bf(v0.w) << 16);
        w.z = f2bf(v1.x) | ((unsigned)f2bf(v1.y) << 16);
        w.w = f2bf(v1.z) | ((unsigned)f2bf(v1.w) << 16);
        *(uint4*)&Abt[(r * 25 + g) * 8] = w;
    }
    {
        const uint4* src = (const uint4*)Wt_g + (size_t)k * 1152;
        uint4* dst = (uint4*)Wt;
        #pragma unroll
        for (int it = 0; it < 5; ++it) {
            int idx = tid + it * 256;
            if (idx < 1152) dst[idx] = src[idx];
        }
        const uint4* src2 = (const uint4*)Dw_g + (size_t)k * 768;
        uint4* dst2 = (uint4*)Dw;
        #pragma unroll
        for (int it = 0; it < 3; ++it) dst2[tid + it * 256] = src2[tid + it * 256];
    }
    ((uint4*)pjd)[tid] = make_uint4(0, 0, 0, 0);   // all 256 uint4s
    __syncthreads();

    const int wv = tid >> 6;
    const int ln = tid & 63;
    const int rw = ln & 15;
    const int kq = ln >> 4;

    // ---- GEMM1 ----
    f32x4 acc0 = {0.f, 0.f, 0.f, 0.f}, acc1 = acc0, acc2 = acc0;
    #pragma unroll
    for (int ks = 0; ks < 6; ++ks) {
        int kg = ks * 4 + kq;
        bf16x8 a  = *(const bf16x8*)&Abt[((wv * 16 + rw) * 25 + kg) * 8];
        bf16x8 b0 = *(const bf16x8*)&Wt[(kg * 48 + rw) * 8];
        bf16x8 b1 = *(const bf16x8*)&Wt[(kg * 48 + 16 + rw) * 8];
        bf16x8 b2 = *(const bf16x8*)&Wt[(kg * 48 + 32 + rw) * 8];
        acc0 = __builtin_amdgcn_mfma_f32_16x16x32_bf16(a, b0, acc0, 0, 0, 0);
        acc1 = __builtin_amdgcn_mfma_f32_16x16x32_bf16(a, b1, acc1, 0, 0, 0);
        acc2 = __builtin_amdgcn_mfma_f32_16x16x32_bf16(a, b2, acc2, 0, 0, 0);
    }
    #pragma unroll
    for (int i = 0; i < 4; ++i) {
        int row = wv * 16 + kq * 4 + i;
        pj[row][rw]      = acc0[i];
        pj[row][16 + rw] = acc1[i];
        pj[row][32 + rw] = acc2[i];
        if (rw < D_RK) pjd[row * 32 + rw] = f2bf(acc0[i]);
    }
    __syncthreads();

    // ---- GEMM2: delta logits ----
    bf16x8 a2 = *(const bf16x8*)&pjd[(wv * 16 + rw) * 32 + kq * 8];
    f32x4 d2[12];
    #pragma unroll
    for (int nt = 0; nt < 12; ++nt) {
        bf16x8 b2 = *(const bf16x8*)&Dw[(kq * 192 + nt * 16 + rw) * 8];
        f32x4 z = {0.f, 0.f, 0.f, 0.f};
        d2[nt] = __builtin_amdgcn_mfma_f32_16x16x32_bf16(a2, b2, z, 0, 0, 0);
    }

    int rowv[4], tep[4];
    #pragma unroll
    for (int i = 0; i < 4; ++i) {
        rowv[i] = wv * 16 + kq * 4 + i;
        tep[i] = scan_map(k, l0 + rowv[i]);
    }
    #pragma unroll
    for (int nt = 0; nt < 12; ++nt) {
        int c = nt * 16 + rw;
        float dtb2 = 2.f * dtb[k * C_DIM + c];
        #pragma unroll
        for (int i = 0; i < 4; ++i) {
            float s = d2[nt][i] + dtb2;
            float sp = (s > 15.f) ? s : __logf(1.f + __expf(s));
            float u = xc[((size_t)(m0 + rowv[i])) * C_DIM + c];
            size_t oi = ((size_t)kbi * L_SZ + tep[i]) * C_DIM + c;
            dq[oi] = ((unsigned)f2bf(sp) << 16) | (unsigned)f2bf(sp * u);
        }
    }
    #pragma unroll
    for (int j = 0; j < 4; ++j) {
        int o = tid + j * 256;               // 1024 = 64*16
        int ll = o >> 4, n = o & 15;
        int te = scan_map(k, l0 + ll);
        size_t oo = ((size_t)kbi * L_SZ + te) * N_ST + n;
        Bm[oo] = pj[ll][D_RK + n];
        Cm[oo] = pj[ll][D_RK + N_ST + n];
    }
}

// ---- chunked scan, lane = (channel, 4 states), packed bf16 delta/du loads ----
// S1: Aprod(float4) -> dense xs scratch, Bsum(float4) -> hb.
__global__ __launch_bounds__(256) void scan_part1(const unsigned* __restrict__ dq,
        const float* __restrict__ Bm, const float* __restrict__ A_logs,
        float* __restrict__ Apr, float* __restrict__ hb)
{
    __shared__ float B_s[TCHUNK][16];
    const int c0 = blockIdx.x * 64;
    const int kb = blockIdx.y;
    const int k = kb >> 1;
    const int ch = blockIdx.z;
    const int tid = threadIdx.x;
    ((float4*)B_s)[tid] = ((const float4*)(Bm + ((size_t)kb * L_SZ + ch * TCHUNK) * N_ST))[tid];
    __syncthreads();

    const int w = tid >> 6, ln = tid & 63;
    const int cl = ln & 15, g = ln >> 4;
    const int c = c0 + w * 16 + cl;
    const float4 Alg = *(const float4*)&A_logs[((size_t)k * C_DIM + c) * N_ST + g * 4];
    const float An0 = -__expf(Alg.x) * 1.44269504089f;
    const float An1 = -__expf(Alg.y) * 1.44269504089f;
    const float An2 = -__expf(Alg.z) * 1.44269504089f;
    const float An3 = -__expf(Alg.w) * 1.44269504089f;
    const unsigned* pq = dq + ((size_t)kb * L_SZ + ch * TCHUNK) * C_DIM + c;
    float h0 = 0.f, h1 = 0.f, h2 = 0.f, h3 = 0.f, dsum = 0.f;
    #pragma unroll 4
    for (int t = 0; t < TCHUNK; ++t) {
        unsigned pk = pq[(size_t)t * C_DIM];
        float dlt = bfhi(pk);
        float qv  = bflo(pk);
        float4 B4 = *(const float4*)&B_s[t][g * 4];
        dsum += dlt;
        h0 = fmaf(__builtin_amdgcn_exp2f(dlt * An0), h0, qv * B4.x);
        h1 = fmaf(__builtin_amdgcn_exp2f(dlt * An1), h1, qv * B4.y);
        h2 = fmaf(__builtin_amdgcn_exp2f(dlt * An2), h2, qv * B4.z);
        h3 = fmaf(__builtin_amdgcn_exp2f(dlt * An3), h3, qv * B4.w);
    }
    unsigned o = ((unsigned)(ch * K_DIR * B_SZ + kb) * C_DIM + c) * N_ST + g * 4;
    float4 Ap4;
    Ap4.x = __builtin_amdgcn_exp2f(dsum * An0);
    Ap4.y = __builtin_amdgcn_exp2f(dsum * An1);
    Ap4.z = __builtin_amdgcn_exp2f(dsum * An2);
    Ap4.w = __builtin_amdgcn_exp2f(dsum * An3);
    *(float4*)&Apr[o] = Ap4;
    *(float4*)&hb[o] = make_float4(h0, h1, h2, h3);
}

// S2: sequential compose over chunks; hb: reads Bsum, writes hinit (same buffer).
__global__ __launch_bounds__(256) void scan_part2(const float* __restrict__ Apr,
        float* hb)
{
    const int kb = blockIdx.y;
    const int wave = threadIdx.x >> 6;
    const int lane = threadIdx.x & 63;
    const int ci = lane >> 4;
    const int n = lane & 15;
    const int c = blockIdx.x * 16 + wave * 4 + ci;
    float h = 0.f;
    #pragma unroll 8
    for (int ch = 0; ch < NCHUNK; ++ch) {
        unsigned o = ((unsigned)(ch * K_DIR * B_SZ + kb) * C_DIM + c) * N_ST + n;
        float Ap = Apr[o];
        float Bs = hb[o];
        hb[o] = h;                 // hinit (exclusive prefix)
        h = fmaf(Ap, h, Bs);
    }
}

// S3: re-run chunk from hinit; y = sum_n h*C -> ysb (bf16).
__global__ __launch_bounds__(256) void scan_part3(const unsigned* __restrict__ dq,
        const float* __restrict__ Bm, const float* __restrict__ Cm,
        const float* __restrict__ A_logs, const float* __restrict__ hb,
        unsigned short* __restrict__ ysb)
{
    __shared__ float B_s[TCHUNK][16];
    __shared__ float C_s[TCHUNK][16];
    const int c0 = blockIdx.x * 64;
    const int kb = blockIdx.y;
    const int k = kb >> 1;
    const int ch = blockIdx.z;
    const int tid = threadIdx.x;
    ((float4*)B_s)[tid] = ((const float4*)(Bm + ((size_t)kb * L_SZ + ch * TCHUNK) * N_ST))[tid];
    ((float4*)C_s)[tid] = ((const float4*)(Cm + ((size_t)kb * L_SZ + ch * TCHUNK) * N_ST))[tid];
    __syncthreads();

    const int w = tid >> 6, ln = tid & 63;
    const int cl = ln & 15, g = ln >> 4;
    const int c = c0 + w * 16 + cl;
    const float4 Alg = *(const float4*)&A_logs[((size_t)k * C_DIM + c) * N_ST + g * 4];
    const float An0 = -__expf(Alg.x) * 1.44269504089f;
    const float An1 = -__expf(Alg.y) * 1.44269504089f;
    const float An2 = -__expf(Alg.z) * 1.44269504089f;
    const float An3 = -__expf(Alg.w) * 1.44269504089f;
    const size_t tbase = ((size_t)kb * L_SZ + ch * TCHUNK) * C_DIM + c;
    const unsigned* pq = dq + tbase;
    unsigned short* yp = ysb + tbase;
    unsigned o = ((unsigned)(ch * K_DIR * B_SZ + kb) * C_DIM + c) * N_ST + g * 4;
    float4 hv = *(const float4*)&hb[o];
    float h0 = hv.x, h1 = hv.y, h2 = hv.z, h3 = hv.w;
    #pragma unroll 4
    for (int t = 0; t < TCHUNK; ++t) {
        unsigned pk = pq[(size_t)t * C_DIM];
        float dlt = bfhi(pk);
        float qv  = bflo(pk);
        float4 B4 = *(const float4*)&B_s[t][g * 4];
        float4 C4 = *(const float4*)&C_s[t][g * 4];
        h0 = fmaf(__builtin_amdgcn_exp2f(dlt * An0), h0, qv * B4.x);
        h1 = fmaf(__builtin_amdgcn_exp2f(dlt * An1), h1, qv * B4.y);
        h2 = fmaf(__builtin_amdgcn_exp2f(dlt * An2), h2, qv * B4.z);
        h3 = fmaf(__builtin_amdgcn_exp2f(dlt * An3), h3, qv * B4.w);
        float p = h0 * C4.x;
        p = fmaf(h1, C4.y, p);
        p = fmaf(h2, C4.z, p);
        p = fmaf(h3, C4.w, p);
        p += __shfl_xor(p, 16);
        p += __shfl_xor(p, 32);
        if (g == 0) yp[(size_t)t * C_DIM] = f2bf(p);
    }
}

// fused: gather 4 dirs (bf16 ys) + Ds*xc + LayerNorm + *silu(z) + out GEMM.
__global__ __launch_bounds__(256) void ln_gemm_fused(const unsigned short* __restrict__ ysb,
        const float* __restrict__ zb, const float* __restrict__ xc,
        const float* __restrict__ Dsv, const float* __restrict__ g,
        const float* __restrict__ bb, const unsigned short* __restrict__ Wout,
        float* __restrict__ outp)
{
    __shared__ __align__(16) unsigned short Abt[32 * 25 * 8];
    __shared__ float ds4s[C_DIM];
    const int tid = threadIdx.x;
    const int m0 = blockIdx.x * 32;

    if (tid < C_DIM)
        ds4s[tid] = Dsv[tid] + Dsv[C_DIM + tid] + Dsv[2 * C_DIM + tid] + Dsv[3 * C_DIM + tid];
    __syncthreads();

    // ---- phase 1: LN + silu -> bf16 fragments ----
    {
        const int r = tid >> 3;            // row 0..31
        const int t8 = tid & 7;            // 8 threads per row, 24 cols each
        const int row = m0 + r;
        const int b = row >> 12, l = row & (L_SZ - 1);
        const int l2 = ((l & 63) << 6) | (l >> 6);
        const unsigned short* r0 = ysb + ((size_t)(0 * B_SZ + b) * L_SZ + l) * C_DIM;
        const unsigned short* r1 = ysb + ((size_t)(1 * B_SZ + b) * L_SZ + (L_SZ - 1 - l)) * C_DIM;
        const unsigned short* r2 = ysb + ((size_t)(2 * B_SZ + b) * L_SZ + l2) * C_DIM;
        const unsigned short* r3 = ysb + ((size_t)(3 * B_SZ + b) * L_SZ + (L_SZ - 1 - l2)) * C_DIM;
        const float* xcr = xc + (size_t)row * C_DIM;
        float4 v[6];
        float s = 0.f, s2 = 0.f;
        #pragma unroll
        for (int q = 0; q < 6; ++q) {
            int cc = t8 * 24 + q * 4;
            ushort4 a0 = *(const ushort4*)&r0[cc];
            ushort4 a1 = *(const ushort4*)&r1[cc];
            ushort4 a2 = *(const ushort4*)&r2[cc];
            ushort4 a3 = *(const ushort4*)&r3[cc];
            float4 xv = *(const float4*)&xcr[cc];
            float4 dd = *(const float4*)&ds4s[cc];
            float4 vv;
            vv.x = bf2f(a0.x) + bf2f(a1.x) + bf2f(a2.x) + bf2f(a3.x) + dd.x * xv.x;
            vv.y = bf2f(a0.y) + bf2f(a1.y) + bf2f(a2.y) + bf2f(a3.y) + dd.y * xv.y;
            vv.z = bf2f(a0.z) + bf2f(a1.z) + bf2f(a2.z) + bf2f(a3.z) + dd.z * xv.z;
            vv.w = bf2f(a0.w) + bf2f(a1.w) + bf2f(a2.w) + bf2f(a3.w) + dd.w * xv.w;
            v[q] = vv;
            s += vv.x + vv.y + vv.z + vv.w;
            s2 += vv.x * vv.x + vv.y * vv.y + vv.z * vv.z + vv.w * vv.w;
        }
        s += __shfl_xor(s, 1); s2 += __shfl_xor(s2, 1);
        s += __shfl_xor(s, 2); s2 += __shfl_xor(s2, 2);
        s += __shfl_xor(s, 4); s2 += __shfl_xor(s2, 4);
        float mu = s / C_DIM;
        float var = s2 / C_DIM - mu * mu;
        float rstd = rsqrtf(var + 1e-5f);
        const float* zr = zb + (size_t)row * C_DIM;
        unsigned short ob[24];
        #pragma unroll
        for (int q = 0; q < 6; ++q) {
            int cc = t8 * 24 + q * 4;
            float4 gv = *(const float4*)&g[cc];
            float4 bv = *(const float4*)&bb[cc];
            float4 zv = *(const float4*)&zr[cc];
            float t0 = (v[q].x - mu) * rstd * gv.x + bv.x;
            float t1 = (v[q].y - mu) * rstd * gv.y + bv.y;
            float t2 = (v[q].z - mu) * rstd * gv.z + bv.z;
            float t3 = (v[q].w - mu) * rstd * gv.w + bv.w;
            ob[q * 4 + 0] = f2bf(t0 * (zv.x * sigmoidf_(zv.x)));
            ob[q * 4 + 1] = f2bf(t1 * (zv.y * sigmoidf_(zv.y)));
            ob[q * 4 + 2] = f2bf(t2 * (zv.z * sigmoidf_(zv.z)));
            ob[q * 4 + 3] = f2bf(t3 * (zv.w * sigmoidf_(zv.w)));
        }
        #pragma unroll
        for (int gi = 0; gi < 3; ++gi) {
            uint4 w;
            w.x = ob[gi * 8 + 0] | ((unsigned)ob[gi * 8 + 1] << 16);
            w.y = ob[gi * 8 + 2] | ((unsigned)ob[gi * 8 + 3] << 16);
            w.z = ob[gi * 8 + 4] | ((unsigned)ob[gi * 8 + 5] << 16);
            w.w = ob[gi * 8 + 6] | ((unsigned)ob[gi * 8 + 7] << 16);
            *(uint4*)&Abt[(r * 25 + t8 * 3 + gi) * 8] = w;
        }
    }
    __syncthreads();

    // ---- phase 2: out GEMM ----
    const int wv = tid >> 6;
    const int ln = tid & 63;
    const int rw = ln & 15;
    const int kq = ln >> 4;
    const int mt = wv >> 1;
    const int nh = wv & 1;

    f32x4 acc[6];
    #pragma unroll
    for (int nt = 0; nt < 6; ++nt) acc[nt] = (f32x4){0.f, 0.f, 0.f, 0.f};
    #pragma unroll
    for (int ks = 0; ks < 6; ++ks) {
        int kg = ks * 4 + kq;
        bf16x8 a = *(const bf16x8*)&Abt[((mt * 16 + rw) * 25 + kg) * 8];
        #pragma unroll
        for (int nt = 0; nt < 6; ++nt) {
            int col = nh * 96 + nt * 16 + rw;
            bf16x8 b = *(const bf16x8*)&Wout[((size_t)kg * C_DIM + col) * 8];
            acc[nt] = __builtin_amdgcn_mfma_f32_16x16x32_bf16(a, b, acc[nt], 0, 0, 0);
        }
    }
    #pragma unroll
    for (int nt = 0; nt < 6; ++nt)
        #pragma unroll
        for (int i = 0; i < 4; ++i) {
            int row = m0 + mt * 16 + kq * 4 + i;
            int col = nh * 96 + nt * 16 + rw;
            outp[(size_t)row * C_DIM + col] = acc[nt][i];
        }
}

extern "C" void kernel_launch(void* const* d_in, const int* in_sizes, int n_in,
                              void* d_out, int out_size, void* d_ws, size_t ws_size,
                              hipStream_t stream)
{
    const float* x         = (const float*)d_in[0];
    const float* in_proj_w = (const float*)d_in[1];
    const float* conv_w    = (const float*)d_in[2];
    const float* conv_b    = (const float*)d_in[3];
    const float* x_proj_w  = (const float*)d_in[4];
    const float* dt_w      = (const float*)d_in[5];
    const float* dt_b      = (const float*)d_in[6];
    const float* A_logs    = (const float*)d_in[7];
    const float* Ds        = (const float*)d_in[8];
    const float* ln_g      = (const float*)d_in[9];
    const float* ln_b      = (const float*)d_in[10];
    const float* out_w     = (const float*)d_in[11];
    float* out = (float*)d_out;
    float* ws = (float*)d_ws;

    const size_t M = (size_t)B_SZ * L_SZ;          // 8192
    const size_t KM = (size_t)K_DIR * M;           // 32768
    const size_t HBSZ = (size_t)NCHUNK * K_DIR * B_SZ * C_DIM * N_ST;  // 1.57M floats

    float* xs      = ws;                           // M*192 (dead after conv -> Apr, exact fit)
    float* zb      = xs + M * C_DIM;               // M*192
    float* xc      = zb + M * C_DIM;               // M*192
    unsigned* dq   = (unsigned*)(xc + M * C_DIM);  // KM*192 packed bf16 (delta,du)
    unsigned short* ysb = (unsigned short*)(dq + KM * C_DIM);  // KM*192 bf16
    float* Bm      = (float*)(ysb + KM * C_DIM);   // KM*16
    float* Cm      = Bm + KM * N_ST;               // KM*16
    float* hb      = Cm + KM * N_ST;               // HBSZ : Bsum then hinit
    float* Apr     = xs;                           // dense reuse, exact size match
    unsigned short* Wt_g = (unsigned short*)(hb + HBSZ);   // 4*9216
    unsigned short* Dw_g = Wt_g + 4 * 9216;                // 4*6144
    unsigned short* Wip  = Dw_g + 4 * 6144;                // 73728
    unsigned short* Wout = Wip + 73728;                    // 36864

    wconv_all<<<dim3(672), 256, 0, stream>>>(in_proj_w, x_proj_w, dt_w, out_w, Wip, Wt_g, Dw_g, Wout);
    gemm_inproj<<<dim3(M / 32, 2), 256, 0, stream>>>(x, Wip, xs, zb);
    conv_silu<<<dim3(H_SZ, 2, B_SZ), 192, 0, stream>>>(xs, conv_w, conv_b, xc);
    proj_mfma<<<dim3(M / 64, K_DIR), 256, 0, stream>>>(xc, Wt_g, Dw_g, dt_b, dq, Bm, Cm);
    scan_part1<<<dim3(C_DIM / 64, K_DIR * B_SZ, NCHUNK), 256, 0, stream>>>(dq, Bm, A_logs, Apr, hb);
    scan_part2<<<dim3(C_DIM / 16, K_DIR * B_SZ), 256, 0, stream>>>(Apr, hb);
    scan_part3<<<dim3(C_DIM / 64, K_DIR * B_SZ, NCHUNK), 256, 0, stream>>>(dq, Bm, Cm, A_logs, hb, ysb);
    ln_gemm_fused<<<dim3(M / 32), 256, 0, stream>>>(ysb, zb, xc, Ds, ln_g, ln_b, Wout, out);
}

// Round 15
// 114.490 us; speedup vs baseline: 1.2086x; 1.0787x over previous
//
#include <hip/hip_runtime.h>
#include <math.h>

#define C_DIM 192
#define N_ST 16
#define K_DIR 4
#define D_RK 12
#define B_SZ 2
#define H_SZ 64
#define W_SZ 64
#define L_SZ 4096
#define DPROJ 44   // D_RK + 2*N_ST
#define NCHUNK 64
#define TCHUNK 64  // L_SZ / NCHUNK

typedef short bf16x8 __attribute__((ext_vector_type(8)));
typedef float f32x4 __attribute__((ext_vector_type(4)));

__device__ __forceinline__ float sigmoidf_(float x) { return 1.f / (1.f + __expf(-x)); }

__device__ __forceinline__ unsigned short f2bf(float f) {
    unsigned u = __builtin_bit_cast(unsigned, f);
    return (unsigned short)((u + 0x7FFFu + ((u >> 16) & 1u)) >> 16);
}
__device__ __forceinline__ float bf2f(unsigned short s) {
    return __builtin_bit_cast(float, (unsigned)s << 16);
}
__device__ __forceinline__ float bfhi(unsigned p) {
    return __builtin_bit_cast(float, p & 0xFFFF0000u);
}
__device__ __forceinline__ float bflo(unsigned p) {
    return __builtin_bit_cast(float, p << 16);
}

// scan-order index t <-> memory index l (involution for every k)
__device__ __forceinline__ int scan_map(int k, int t) {
    int te = (k & 1) ? (L_SZ - 1 - t) : t;
    return (k >= 2) ? (((te & 63) << 6) | (te >> 6)) : te;  // transpose HxW (64x64)
}

// ---- one-time weight conversion -> bf16 MFMA fragments ----
__global__ __launch_bounds__(256) void wconv_all(const float* __restrict__ ipw,
        const float* __restrict__ xpw, const float* __restrict__ dtw,
        const float* __restrict__ ow,
        unsigned short* __restrict__ Wip, unsigned short* __restrict__ Wt_g,
        unsigned short* __restrict__ Dw_g, unsigned short* __restrict__ Wout)
{
    int idx = blockIdx.x * 256 + threadIdx.x;   // 0 .. 172031
    if (idx < 73728) {                          // in_proj_w
        int kg = idx / 3072;                    // 384*8
        int rem = idx - kg * 3072;
        int col = rem >> 3, j = rem & 7;
        Wip[idx] = f2bf(ipw[(size_t)(kg * 8 + j) * 384 + col]);
    } else if (idx < 110592) {                  // x_proj_w
        int i2 = idx - 73728;
        int k = i2 / 9216;
        int rem = i2 - k * 9216;
        int kg = rem / 384;
        int r2 = rem - kg * 384;
        int col = r2 >> 3, j = r2 & 7;
        int kr = kg * 8 + j;
        float v = (col < DPROJ) ? xpw[(size_t)k * C_DIM * DPROJ + kr * DPROJ + col] : 0.f;
        Wt_g[i2] = f2bf(v);
    } else if (idx < 135168) {                  // dt_w
        int i3 = idx - 110592;
        int k = i3 / 6144;
        int rem = i3 - k * 6144;
        int kb2 = rem / 1536;
        int r2 = rem - kb2 * 1536;
        int c = r2 >> 3, j = r2 & 7;
        int kr = kb2 * 8 + j;
        float v = (kr < D_RK) ? dtw[(size_t)k * D_RK * C_DIM + kr * C_DIM + c] : 0.f;
        Dw_g[i3] = f2bf(v);
    } else {                                    // out_w
        int i4 = idx - 135168;
        int kg = i4 / 1536;                     // 192*8
        int rem = i4 - kg * 1536;
        int col = rem >> 3, j = rem & 7;
        Wout[i4] = f2bf(ow[(size_t)(kg * 8 + j) * C_DIM + col]);
    }
}

// in_proj MFMA GEMM with split outputs: blockIdx.y==0 -> xs, ==1 -> zb.
__global__ __launch_bounds__(256) void gemm_inproj(const float* __restrict__ A,
        const unsigned short* __restrict__ Wt, float* __restrict__ xs,
        float* __restrict__ zb)
{
    __shared__ __align__(16) unsigned short Abt[32 * 25 * 8];  // 12.8 KB
    const int tid = threadIdx.x;
    const int m0 = blockIdx.x * 32;
    const int col0 = blockIdx.y * 192;
    float* outp = blockIdx.y ? zb : xs;

    #pragma unroll
    for (int it = 0; it < 3; ++it) {
        int idx = tid + it * 256;            // 768 = 32 rows * 24 kg
        int r = idx / 24, g = idx - r * 24;
        const float* src = &A[((size_t)(m0 + r)) * C_DIM + g * 8];
        float4 v0 = *(const float4*)src;
        float4 v1 = *(const float4*)(src + 4);
        uint4 w;
        w.x = f2bf(v0.x) | ((unsigned)f2bf(v0.y) << 16);
        w.y = f2bf(v0.z) | ((unsigned)f2bf(v0.w) << 16);
        w.z = f2bf(v1.x) | ((unsigned)f2bf(v1.y) << 16);
        w.w = f2bf(v1.z) | ((unsigned)f2bf(v1.w) << 16);
        *(uint4*)&Abt[(r * 25 + g) * 8] = w;
    }
    __syncthreads();

    const int wv = tid >> 6;
    const int ln = tid & 63;
    const int rw = ln & 15;
    const int kq = ln >> 4;
    const int mt = wv >> 1;
    const int nh = wv & 1;

    f32x4 acc[6];
    #pragma unroll
    for (int nt = 0; nt < 6; ++nt) acc[nt] = (f32x4){0.f, 0.f, 0.f, 0.f};

    #pragma unroll
    for (int ks = 0; ks < 6; ++ks) {
        int kg = ks * 4 + kq;
        bf16x8 a = *(const bf16x8*)&Abt[((mt * 16 + rw) * 25 + kg) * 8];
        #pragma unroll
        for (int nt = 0; nt < 6; ++nt) {
            int col = col0 + nh * 96 + nt * 16 + rw;
            bf16x8 b = *(const bf16x8*)&Wt[((size_t)kg * 384 + col) * 8];
            acc[nt] = __builtin_amdgcn_mfma_f32_16x16x32_bf16(a, b, acc[nt], 0, 0, 0);
        }
    }
    #pragma unroll
    for (int nt = 0; nt < 6; ++nt)
        #pragma unroll
        for (int i = 0; i < 4; ++i) {
            int row = m0 + mt * 16 + kq * 4 + i;
            int col = nh * 96 + nt * 16 + rw;
            outp[(size_t)row * C_DIM + col] = acc[nt][i];
        }
}

// depthwise 3x3 SAME conv + bias + SiLU: xs -> xc. w-tiles of 8 (4 blocks/CU).
__global__ __launch_bounds__(192) void conv_silu(const float* __restrict__ xs,
        const float* __restrict__ cw, const float* __restrict__ cb, float* __restrict__ xc)
{
    const int c = threadIdx.x;
    const int h = blockIdx.x;
    const int w0 = blockIdx.y * 8;
    const int b = blockIdx.z;
    float wg[9];
    #pragma unroll
    for (int i = 0; i < 9; ++i) wg[i] = cw[c * 9 + i];
    const float* base = xs + ((size_t)b * L_SZ + (size_t)h * W_SZ) * C_DIM + c;
    const bool hm = (h > 0), hp = (h < H_SZ - 1);
    const int RS = W_SZ * C_DIM;
    float cL[3], cC[3], cR[3];
    #define LDCOL(w, dst) { \
        int off_ = (w) * C_DIM; \
        dst[0] = hm ? base[off_ - RS] : 0.f; \
        dst[1] = base[off_]; \
        dst[2] = hp ? base[off_ + RS] : 0.f; }
    if (w0 > 0) { LDCOL(w0 - 1, cL) } else { cL[0] = cL[1] = cL[2] = 0.f; }
    LDCOL(w0, cC)
    const float bias = cb[c];
    #pragma unroll
    for (int w = w0; w < w0 + 8; ++w) {
        if (w < W_SZ - 1) { LDCOL(w + 1, cR) } else { cR[0] = cR[1] = cR[2] = 0.f; }
        float acc = bias;
        #pragma unroll
        for (int r = 0; r < 3; ++r)
            acc += cL[r] * wg[r * 3] + cC[r] * wg[r * 3 + 1] + cR[r] * wg[r * 3 + 2];
        float v = acc * sigmoidf_(acc);
        xc[((size_t)b * L_SZ + h * W_SZ + w) * C_DIM + c] = v;
        cL[0] = cC[0]; cL[1] = cC[1]; cL[2] = cC[2];
        cC[0] = cR[0]; cC[1] = cR[1]; cC[2] = cR[2];
    }
    #undef LDCOL
}

// MFMA proj: block = 64 memory-order rows x one direction; scatter writes.
// u read from the staged LDS Abt tile (no global xc re-read).
__global__ __launch_bounds__(256) void proj_mfma(const float* __restrict__ xc,
        const unsigned short* __restrict__ Wt_g, const unsigned short* __restrict__ Dw_g,
        const float* __restrict__ dtb,
        unsigned* __restrict__ dq,
        float* __restrict__ Bm, float* __restrict__ Cm)
{
    __shared__ __align__(16) unsigned short Abt[64 * 25 * 8];
    __shared__ __align__(16) unsigned short Wt[24 * 48 * 8];
    __shared__ __align__(16) unsigned short Dw[4 * 192 * 8];
    __shared__ __align__(16) unsigned short pjd[64 * 32];
    __shared__ float pj[64][50];

    const int tid = threadIdx.x;
    const int m0 = blockIdx.x * 64;
    const int b  = m0 >> 12;
    const int l0 = m0 & (L_SZ - 1);
    const int k  = blockIdx.y;
    const int kbi = k * B_SZ + b;

    #pragma unroll
    for (int it = 0; it < 6; ++it) {
        int idx = tid + it * 256;            // 1536 = 64 rows * 24 kgroups
        int r = idx / 24, g = idx - r * 24;
        const float* src = &xc[((size_t)(m0 + r)) * C_DIM + g * 8];
        float4 v0 = *(const float4*)src;
        float4 v1 = *(const float4*)(src + 4);
        uint4 w;
        w.x = f2bf(v0.x) | ((unsigned)f2bf(v0.y) << 16);
        w.y = f2bf(v0.z) | ((unsigned)f2bf(v0.w) << 16);
        w.z = f2bf(v1.x) | ((unsigned)f2bf(v1.y) << 16);
        w.w = f2bf(v1.z) | ((unsigned)f2bf(v1.w) << 16);
        *(uint4*)&Abt[(r * 25 + g) * 8] = w;
    }
    {
        const uint4* src = (const uint4*)Wt_g + (size_t)k * 1152;
        uint4* dst = (uint4*)Wt;
        #pragma unroll
        for (int it = 0; it < 5; ++it) {
            int idx = tid + it * 256;
            if (idx < 1152) dst[idx] = src[idx];
        }
        const uint4* src2 = (const uint4*)Dw_g + (size_t)k * 768;
        uint4* dst2 = (uint4*)Dw;
        #pragma unroll
        for (int it = 0; it < 3; ++it) dst2[tid + it * 256] = src2[tid + it * 256];
    }
    ((uint4*)pjd)[tid] = make_uint4(0, 0, 0, 0);   // all 256 uint4s
    __syncthreads();

    const int wv = tid >> 6;
    const int ln = tid & 63;
    const int rw = ln & 15;
    const int kq = ln >> 4;

    // ---- GEMM1 ----
    f32x4 acc0 = {0.f, 0.f, 0.f, 0.f}, acc1 = acc0, acc2 = acc0;
    #pragma unroll
    for (int ks = 0; ks < 6; ++ks) {
        int kg = ks * 4 + kq;
        bf16x8 a  = *(const bf16x8*)&Abt[((wv * 16 + rw) * 25 + kg) * 8];
        bf16x8 b0 = *(const bf16x8*)&Wt[(kg * 48 + rw) * 8];
        bf16x8 b1 = *(const bf16x8*)&Wt[(kg * 48 + 16 + rw) * 8];
        bf16x8 b2 = *(const bf16x8*)&Wt[(kg * 48 + 32 + rw) * 8];
        acc0 = __builtin_amdgcn_mfma_f32_16x16x32_bf16(a, b0, acc0, 0, 0, 0);
        acc1 = __builtin_amdgcn_mfma_f32_16x16x32_bf16(a, b1, acc1, 0, 0, 0);
        acc2 = __builtin_amdgcn_mfma_f32_16x16x32_bf16(a, b2, acc2, 0, 0, 0);
    }
    #pragma unroll
    for (int i = 0; i < 4; ++i) {
        int row = wv * 16 + kq * 4 + i;
        pj[row][rw]      = acc0[i];
        pj[row][16 + rw] = acc1[i];
        pj[row][32 + rw] = acc2[i];
        if (rw < D_RK) pjd[row * 32 + rw] = f2bf(acc0[i]);
    }
    __syncthreads();

    // ---- GEMM2: delta logits ----
    bf16x8 a2 = *(const bf16x8*)&pjd[(wv * 16 + rw) * 32 + kq * 8];
    f32x4 d2[12];
    #pragma unroll
    for (int nt = 0; nt < 12; ++nt) {
        bf16x8 b2 = *(const bf16x8*)&Dw[(kq * 192 + nt * 16 + rw) * 8];
        f32x4 z = {0.f, 0.f, 0.f, 0.f};
        d2[nt] = __builtin_amdgcn_mfma_f32_16x16x32_bf16(a2, b2, z, 0, 0, 0);
    }

    int rowv[4], tep[4];
    #pragma unroll
    for (int i = 0; i < 4; ++i) {
        rowv[i] = wv * 16 + kq * 4 + i;
        tep[i] = scan_map(k, l0 + rowv[i]);
    }
    #pragma unroll
    for (int nt = 0; nt < 12; ++nt) {
        int c = nt * 16 + rw;
        int g8 = c >> 3, j = c & 7;
        float dtb2 = 2.f * dtb[k * C_DIM + c];
        #pragma unroll
        for (int i = 0; i < 4; ++i) {
            float s = d2[nt][i] + dtb2;
            float sp = (s > 15.f) ? s : __logf(1.f + __expf(s));
            float u = bf2f(Abt[(rowv[i] * 25 + g8) * 8 + j]);
            size_t oi = ((size_t)kbi * L_SZ + tep[i]) * C_DIM + c;
            dq[oi] = ((unsigned)f2bf(sp) << 16) | (unsigned)f2bf(sp * u);
        }
    }
    #pragma unroll
    for (int j = 0; j < 4; ++j) {
        int o = tid + j * 256;               // 1024 = 64*16
        int ll = o >> 4, n = o & 15;
        int te = scan_map(k, l0 + ll);
        size_t oo = ((size_t)kbi * L_SZ + te) * N_ST + n;
        Bm[oo] = pj[ll][D_RK + n];
        Cm[oo] = pj[ll][D_RK + N_ST + n];
    }
}

// ---- chunked scan, lane = (channel, 4 states), packed bf16 delta/du loads ----
// S1: Aprod(float4) -> dense xs scratch, Bsum(float4) -> hb.
__global__ __launch_bounds__(256) void scan_part1(const unsigned* __restrict__ dq,
        const float* __restrict__ Bm, const float* __restrict__ A_logs,
        float* __restrict__ Apr, float* __restrict__ hb)
{
    __shared__ float B_s[TCHUNK][16];
    const int c0 = blockIdx.x * 64;
    const int kb = blockIdx.y;
    const int k = kb >> 1;
    const int ch = blockIdx.z;
    const int tid = threadIdx.x;
    ((float4*)B_s)[tid] = ((const float4*)(Bm + ((size_t)kb * L_SZ + ch * TCHUNK) * N_ST))[tid];
    __syncthreads();

    const int w = tid >> 6, ln = tid & 63;
    const int cl = ln & 15, g = ln >> 4;
    const int c = c0 + w * 16 + cl;
    const float4 Alg = *(const float4*)&A_logs[((size_t)k * C_DIM + c) * N_ST + g * 4];
    const float An0 = -__expf(Alg.x) * 1.44269504089f;
    const float An1 = -__expf(Alg.y) * 1.44269504089f;
    const float An2 = -__expf(Alg.z) * 1.44269504089f;
    const float An3 = -__expf(Alg.w) * 1.44269504089f;
    const unsigned* pq = dq + ((size_t)kb * L_SZ + ch * TCHUNK) * C_DIM + c;
    float h0 = 0.f, h1 = 0.f, h2 = 0.f, h3 = 0.f, dsum = 0.f;
    #pragma unroll 4
    for (int t = 0; t < TCHUNK; ++t) {
        unsigned pk = pq[(size_t)t * C_DIM];
        float dlt = bfhi(pk);
        float qv  = bflo(pk);
        float4 B4 = *(const float4*)&B_s[t][g * 4];
        dsum += dlt;
        h0 = fmaf(__builtin_amdgcn_exp2f(dlt * An0), h0, qv * B4.x);
        h1 = fmaf(__builtin_amdgcn_exp2f(dlt * An1), h1, qv * B4.y);
        h2 = fmaf(__builtin_amdgcn_exp2f(dlt * An2), h2, qv * B4.z);
        h3 = fmaf(__builtin_amdgcn_exp2f(dlt * An3), h3, qv * B4.w);
    }
    unsigned o = ((unsigned)(ch * K_DIR * B_SZ + kb) * C_DIM + c) * N_ST + g * 4;
    float4 Ap4;
    Ap4.x = __builtin_amdgcn_exp2f(dsum * An0);
    Ap4.y = __builtin_amdgcn_exp2f(dsum * An1);
    Ap4.z = __builtin_amdgcn_exp2f(dsum * An2);
    Ap4.w = __builtin_amdgcn_exp2f(dsum * An3);
    *(float4*)&Apr[o] = Ap4;
    *(float4*)&hb[o] = make_float4(h0, h1, h2, h3);
}

// S2: sequential compose over chunks; hb: reads Bsum, writes hinit (same buffer).
__global__ __launch_bounds__(256) void scan_part2(const float* __restrict__ Apr,
        float* hb)
{
    const int kb = blockIdx.y;
    const int wave = threadIdx.x >> 6;
    const int lane = threadIdx.x & 63;
    const int ci = lane >> 4;
    const int n = lane & 15;
    const int c = blockIdx.x * 16 + wave * 4 + ci;
    float h = 0.f;
    #pragma unroll 8
    for (int ch = 0; ch < NCHUNK; ++ch) {
        unsigned o = ((unsigned)(ch * K_DIR * B_SZ + kb) * C_DIM + c) * N_ST + n;
        float Ap = Apr[o];
        float Bs = hb[o];
        hb[o] = h;                 // hinit (exclusive prefix)
        h = fmaf(Ap, h, Bs);
    }
}

// S3: re-run chunk from hinit; y = sum_n h*C -> ysb (bf16).
__global__ __launch_bounds__(256) void scan_part3(const unsigned* __restrict__ dq,
        const float* __restrict__ Bm, const float* __restrict__ Cm,
        const float* __restrict__ A_logs, const float* __restrict__ hb,
        unsigned short* __restrict__ ysb)
{
    __shared__ float B_s[TCHUNK][16];
    __shared__ float C_s[TCHUNK][16];
    const int c0 = blockIdx.x * 64;
    const int kb = blockIdx.y;
    const int k = kb >> 1;
    const int ch = blockIdx.z;
    const int tid = threadIdx.x;
    ((float4*)B_s)[tid] = ((const float4*)(Bm + ((size_t)kb * L_SZ + ch * TCHUNK) * N_ST))[tid];
    ((float4*)C_s)[tid] = ((const float4*)(Cm + ((size_t)kb * L_SZ + ch * TCHUNK) * N_ST))[tid];
    __syncthreads();

    const int w = tid >> 6, ln = tid & 63;
    const int cl = ln & 15, g = ln >> 4;
    const int c = c0 + w * 16 + cl;
    const float4 Alg = *(const float4*)&A_logs[((size_t)k * C_DIM + c) * N_ST + g * 4];
    const float An0 = -__expf(Alg.x) * 1.44269504089f;
    const float An1 = -__expf(Alg.y) * 1.44269504089f;
    const float An2 = -__expf(Alg.z) * 1.44269504089f;
    const float An3 = -__expf(Alg.w) * 1.44269504089f;
    const size_t tbase = ((size_t)kb * L_SZ + ch * TCHUNK) * C_DIM + c;
    const unsigned* pq = dq + tbase;
    unsigned short* yp = ysb + tbase;
    unsigned o = ((unsigned)(ch * K_DIR * B_SZ + kb) * C_DIM + c) * N_ST + g * 4;
    float4 hv = *(const float4*)&hb[o];
    float h0 = hv.x, h1 = hv.y, h2 = hv.z, h3 = hv.w;
    #pragma unroll 4
    for (int t = 0; t < TCHUNK; ++t) {
        unsigned pk = pq[(size_t)t * C_DIM];
        float dlt = bfhi(pk);
        float qv  = bflo(pk);
        float4 B4 = *(const float4*)&B_s[t][g * 4];
        float4 C4 = *(const float4*)&C_s[t][g * 4];
        h0 = fmaf(__builtin_amdgcn_exp2f(dlt * An0), h0, qv * B4.x);
        h1 = fmaf(__builtin_amdgcn_exp2f(dlt * An1), h1, qv * B4.y);
        h2 = fmaf(__builtin_amdgcn_exp2f(dlt * An2), h2, qv * B4.z);
        h3 = fmaf(__builtin_amdgcn_exp2f(dlt * An3), h3, qv * B4.w);
        float p = h0 * C4.x;
        p = fmaf(h1, C4.y, p);
        p = fmaf(h2, C4.z, p);
        p = fmaf(h3, C4.w, p);
        p += __shfl_xor(p, 16);
        p += __shfl_xor(p, 32);
        if (g == 0) yp[(size_t)t * C_DIM] = f2bf(p);
    }
}

// fused: gather 4 dirs (bf16 ys) + Ds*xc + LayerNorm + *silu(z) + out GEMM.
// 16-row blocks (grid M/16 = 512 -> 2 blocks/CU).
__global__ __launch_bounds__(256) void ln_gemm_fused(const unsigned short* __restrict__ ysb,
        const float* __restrict__ zb, const float* __restrict__ xc,
        const float* __restrict__ Dsv, const float* __restrict__ g,
        const float* __restrict__ bb, const unsigned short* __restrict__ Wout,
        float* __restrict__ outp)
{
    __shared__ __align__(16) unsigned short Abt[16 * 25 * 8];
    __shared__ float ds4s[C_DIM];
    const int tid = threadIdx.x;
    const int m0 = blockIdx.x * 16;

    if (tid < C_DIM)
        ds4s[tid] = Dsv[tid] + Dsv[C_DIM + tid] + Dsv[2 * C_DIM + tid] + Dsv[3 * C_DIM + tid];
    __syncthreads();

    // ---- phase 1: LN + silu -> bf16 fragments (threads 0..127: 8 per row) ----
    if (tid < 128) {
        const int r = tid >> 3;            // row 0..15
        const int t8 = tid & 7;            // 8 threads per row, 24 cols each
        const int row = m0 + r;
        const int b = row >> 12, l = row & (L_SZ - 1);
        const int l2 = ((l & 63) << 6) | (l >> 6);
        const unsigned short* r0 = ysb + ((size_t)(0 * B_SZ + b) * L_SZ + l) * C_DIM;
        const unsigned short* r1 = ysb + ((size_t)(1 * B_SZ + b) * L_SZ + (L_SZ - 1 - l)) * C_DIM;
        const unsigned short* r2 = ysb + ((size_t)(2 * B_SZ + b) * L_SZ + l2) * C_DIM;
        const unsigned short* r3 = ysb + ((size_t)(3 * B_SZ + b) * L_SZ + (L_SZ - 1 - l2)) * C_DIM;
        const float* xcr = xc + (size_t)row * C_DIM;
        float4 v[6];
        float s = 0.f, s2 = 0.f;
        #pragma unroll
        for (int q = 0; q < 6; ++q) {
            int cc = t8 * 24 + q * 4;
            ushort4 a0 = *(const ushort4*)&r0[cc];
            ushort4 a1 = *(const ushort4*)&r1[cc];
            ushort4 a2 = *(const ushort4*)&r2[cc];
            ushort4 a3 = *(const ushort4*)&r3[cc];
            float4 xv = *(const float4*)&xcr[cc];
            float4 dd = *(const float4*)&ds4s[cc];
            float4 vv;
            vv.x = bf2f(a0.x) + bf2f(a1.x) + bf2f(a2.x) + bf2f(a3.x) + dd.x * xv.x;
            vv.y = bf2f(a0.y) + bf2f(a1.y) + bf2f(a2.y) + bf2f(a3.y) + dd.y * xv.y;
            vv.z = bf2f(a0.z) + bf2f(a1.z) + bf2f(a2.z) + bf2f(a3.z) + dd.z * xv.z;
            vv.w = bf2f(a0.w) + bf2f(a1.w) + bf2f(a2.w) + bf2f(a3.w) + dd.w * xv.w;
            v[q] = vv;
            s += vv.x + vv.y + vv.z + vv.w;
            s2 += vv.x * vv.x + vv.y * vv.y + vv.z * vv.z + vv.w * vv.w;
        }
        s += __shfl_xor(s, 1); s2 += __shfl_xor(s2, 1);
        s += __shfl_xor(s, 2); s2 += __shfl_xor(s2, 2);
        s += __shfl_xor(s, 4); s2 += __shfl_xor(s2, 4);
        float mu = s / C_DIM;
        float var = s2 / C_DIM - mu * mu;
        float rstd = rsqrtf(var + 1e-5f);
        const float* zr = zb + (size_t)row * C_DIM;
        unsigned short ob[24];
        #pragma unroll
        for (int q = 0; q < 6; ++q) {
            int cc = t8 * 24 + q * 4;
            float4 gv = *(const float4*)&g[cc];
            float4 bv = *(const float4*)&bb[cc];
            float4 zv = *(const float4*)&zr[cc];
            float t0 = (v[q].x - mu) * rstd * gv.x + bv.x;
            float t1 = (v[q].y - mu) * rstd * gv.y + bv.y;
            float t2 = (v[q].z - mu) * rstd * gv.z + bv.z;
            float t3 = (v[q].w - mu) * rstd * gv.w + bv.w;
            ob[q * 4 + 0] = f2bf(t0 * (zv.x * sigmoidf_(zv.x)));
            ob[q * 4 + 1] = f2bf(t1 * (zv.y * sigmoidf_(zv.y)));
            ob[q * 4 + 2] = f2bf(t2 * (zv.z * sigmoidf_(zv.z)));
            ob[q * 4 + 3] = f2bf(t3 * (zv.w * sigmoidf_(zv.w)));
        }
        #pragma unroll
        for (int gi = 0; gi < 3; ++gi) {
            uint4 w;
            w.x = ob[gi * 8 + 0] | ((unsigned)ob[gi * 8 + 1] << 16);
            w.y = ob[gi * 8 + 2] | ((unsigned)ob[gi * 8 + 3] << 16);
            w.z = ob[gi * 8 + 4] | ((unsigned)ob[gi * 8 + 5] << 16);
            w.w = ob[gi * 8 + 6] | ((unsigned)ob[gi * 8 + 7] << 16);
            *(uint4*)&Abt[(r * 25 + t8 * 3 + gi) * 8] = w;
        }
    }
    __syncthreads();

    // ---- phase 2: out GEMM. 4 waves x (16 rows x 48 cols) ----
    const int wv = tid >> 6;
    const int ln = tid & 63;
    const int rw = ln & 15;
    const int kq = ln >> 4;

    f32x4 acc[3];
    #pragma unroll
    for (int nt = 0; nt < 3; ++nt) acc[nt] = (f32x4){0.f, 0.f, 0.f, 0.f};
    #pragma unroll
    for (int ks = 0; ks < 6; ++ks) {
        int kg = ks * 4 + kq;
        bf16x8 a = *(const bf16x8*)&Abt[(rw * 25 + kg) * 8];
        #pragma unroll
        for (int nt = 0; nt < 3; ++nt) {
            int col = wv * 48 + nt * 16 + rw;
            bf16x8 b = *(const bf16x8*)&Wout[((size_t)kg * C_DIM + col) * 8];
            acc[nt] = __builtin_amdgcn_mfma_f32_16x16x32_bf16(a, b, acc[nt], 0, 0, 0);
        }
    }
    #pragma unroll
    for (int nt = 0; nt < 3; ++nt)
        #pragma unroll
        for (int i = 0; i < 4; ++i) {
            int row = m0 + kq * 4 + i;
            int col = wv * 48 + nt * 16 + rw;
            outp[(size_t)row * C_DIM + col] = acc[nt][i];
        }
}

extern "C" void kernel_launch(void* const* d_in, const int* in_sizes, int n_in,
                              void* d_out, int out_size, void* d_ws, size_t ws_size,
                              hipStream_t stream)
{
    const float* x         = (const float*)d_in[0];
    const float* in_proj_w = (const float*)d_in[1];
    const float* conv_w    = (const float*)d_in[2];
    const float* conv_b    = (const float*)d_in[3];
    const float* x_proj_w  = (const float*)d_in[4];
    const float* dt_w      = (const float*)d_in[5];
    const float* dt_b      = (const float*)d_in[6];
    const float* A_logs    = (const float*)d_in[7];
    const float* Ds        = (const float*)d_in[8];
    const float* ln_g      = (const float*)d_in[9];
    const float* ln_b      = (const float*)d_in[10];
    const float* out_w     = (const float*)d_in[11];
    float* out = (float*)d_out;
    float* ws = (float*)d_ws;

    const size_t M = (size_t)B_SZ * L_SZ;          // 8192
    const size_t KM = (size_t)K_DIR * M;           // 32768
    const size_t HBSZ = (size_t)NCHUNK * K_DIR * B_SZ * C_DIM * N_ST;  // 1.57M floats

    float* xs      = ws;                           // M*192 (dead after conv -> Apr)
    float* zb      = xs + M * C_DIM;               // M*192
    float* xc      = zb + M * C_DIM;               // M*192
    unsigned* dq   = (unsigned*)(xc + M * C_DIM);  // KM*192 packed bf16 (delta,du)
    unsigned short* ysb = (unsigned short*)(dq + KM * C_DIM);  // KM*192 bf16
    float* Bm      = (float*)(ysb + KM * C_DIM);   // KM*16
    float* Cm      = Bm + KM * N_ST;               // KM*16
    float* hb      = Cm + KM * N_ST;               // HBSZ : Bsum then hinit
    float* Apr     = xs;                           // dense reuse, exact size match
    unsigned short* Wt_g = (unsigned short*)(hb + HBSZ);   // 4*9216
    unsigned short* Dw_g = Wt_g + 4 * 9216;                // 4*6144
    unsigned short* Wip  = Dw_g + 4 * 6144;                // 73728
    unsigned short* Wout = Wip + 73728;                    // 36864

    wconv_all<<<dim3(672), 256, 0, stream>>>(in_proj_w, x_proj_w, dt_w, out_w, Wip, Wt_g, Dw_g, Wout);
    gemm_inproj<<<dim3(M / 32, 2), 256, 0, stream>>>(x, Wip, xs, zb);
    conv_silu<<<dim3(H_SZ, 8, B_SZ), 192, 0, stream>>>(xs, conv_w, conv_b, xc);
    proj_mfma<<<dim3(M / 64, K_DIR), 256, 0, stream>>>(xc, Wt_g, Dw_g, dt_b, dq, Bm, Cm);
    scan_part1<<<dim3(C_DIM / 64, K_DIR * B_SZ, NCHUNK), 256, 0, stream>>>(dq, Bm, A_logs, Apr, hb);
    scan_part2<<<dim3(C_DIM / 16, K_DIR * B_SZ), 256, 0, stream>>>(Apr, hb);
    scan_part3<<<dim3(C_DIM / 64, K_DIR * B_SZ, NCHUNK), 256, 0, stream>>>(dq, Bm, Cm, A_logs, hb, ysb);
    ln_gemm_fused<<<dim3(M / 16), 256, 0, stream>>>(ysb, zb, xc, Ds, ln_g, ln_b, Wout, out);
}